// Round 1
// 130.249 us; speedup vs baseline: 1.0060x; 1.0060x over previous
//
#include <hip/hip_runtime.h>

// MWPT: 3-level wavelet packet, KS=8, circular pad(3,3), stride-2.
// y[n] = sum_k x[(2n+k-3) mod T] * w[k];  hi[j] = (-1)^j * ker[7-j]
//
// R7: all-b128 LDS. Replaces R6's +1/16 padding (P(i)=i+(i>>4), scalar
// ds_read_b32/ds_write_b32 everywhere, ~139 LDS ops/thread) with a
// quad-granular XOR swizzle SW(q)=q^((q>>3)&7) (bijective involution inside
// each 128B group). Storage offsets chosen so the output-aligned main
// ranges are also quad-aligned:
//   a_store[s] = a_local[s-3]  -> main jj=8t+9..8t+16 = quads 2t+3,2t+4
//   bs_store[s] = b_local[s-1] -> main m =4t+3..4t+6  = quad  t+1
// Main-path LDS traffic: 6+8+12 ds_read_b128, 4.2+4+4 ds_write_b128
// (~38 ops/thread vs 139 b32). Swizzled bank groups checked per access
// shape: <=2-way per 8-lane group (free on wave64).
// Everything else identical to R6: single-wave blocks (syncthreads =
// waitcnt only), CHUNK=1024, grid 64x128, store widths/orders unchanged.
//
// Output layout (flat, fp32):
//   level1 [128][2][32768]  @ 0          order [a0, a4]
//   level2 [128][4][16384]  @ 8388608    order [b0, b2, b6, b4]
//   level3 [128][8][8192]   @ 16777216   order [c0, c1, c3, c2, c6, c7, c5, c4]

#define T_MASK 65535

__device__ __forceinline__ int SW(int q) { return q ^ ((q >> 3) & 7); }

#define XS_F 1152   // 288 quads (stage 268; bs reuse needs 4*72=288)
#define AS_F 544    // 136 quads (need s<=532 -> quad 133)
#define BS_F 288    // 72 quads  (need s<=262 -> quad 65)

__global__ __launch_bounds__(64) void mwpt_kernel(
    const float* __restrict__ x, const float* __restrict__ ker,
    float* __restrict__ out)
{
    __shared__ __align__(16) float lds[XS_F + 2 * AS_F];   // 2240 floats = 8.96 KB
    float* xs  = lds;
    float* as0 = lds + XS_F;
    float* as1 = lds + XS_F + AS_F;
    float* bs0 = lds;                         // xs region reused after L1
    float* bs1 = lds + BS_F;
    float* bs2 = lds + 2 * BS_F;
    float* bs3 = lds + 3 * BS_F;

    const int t   = threadIdx.x;              // 0..63
    const int seg = blockIdx.x;               // 0..63
    const int bi  = blockIdx.y;               // 0..127
    const int N1  = seg * 512;
    const int N2  = seg * 256;
    const int N3  = seg * 128;
    const float* __restrict__ xrow = x + (size_t)bi * 65536;

    float lo[8], hi[8];
#pragma unroll
    for (int k = 0; k < 8; ++k) lo[k] = ker[k];
#pragma unroll
    for (int k = 0; k < 8; ++k) hi[k] = (k & 1) ? -ker[7 - k] : ker[7 - k];

    // ---- stage x: 268 aligned float4 loads -> swizzled quads (b128 writes) ----
    // xs quad u <-> x[(A + 4u .. A + 4u + 3) mod T], A = 1024*seg - 24
    const int A = 1024 * seg - 24;
    for (int u = t; u < 268; u += 64) {
        int g = (A + 4 * u) & T_MASK;
        float4 v = *(const float4*)(xrow + g);
        *(float4*)(xs + 4 * SW(u)) = v;
    }

    __syncthreads();                          // 1 wave: waitcnt only

    // ---- level 1: a[jj] = sum_k xl[2jj+3+k] * w ; main jj = 8t+9..8t+16 ----
    {
        alignas(16) float xv[24];             // xv[i] = x-local[16t+20+i]
#pragma unroll
        for (int j = 0; j < 6; ++j)
            *(float4*)(xv + 4 * j) = *(const float4*)(xs + 4 * SW(4 * t + 5 + j));
        float r0[8], r4[8];
#pragma unroll
        for (int i = 0; i < 8; ++i) {
            float s0 = 0.f, s4 = 0.f;
#pragma unroll
            for (int k = 0; k < 8; ++k) {
                float v = xv[2 * i + 1 + k];
                s0 += v * lo[k]; s4 += v * hi[k];
            }
            r0[i] = s0; r4[i] = s4;
        }
        // a_store s = jj+3 -> quads 2t+3, 2t+4
        *(float4*)(as0 + 4 * SW(2 * t + 3)) = make_float4(r0[0], r0[1], r0[2], r0[3]);
        *(float4*)(as0 + 4 * SW(2 * t + 4)) = make_float4(r0[4], r0[5], r0[6], r0[7]);
        *(float4*)(as1 + 4 * SW(2 * t + 3)) = make_float4(r4[0], r4[1], r4[2], r4[3]);
        *(float4*)(as1 + 4 * SW(2 * t + 4)) = make_float4(r4[4], r4[5], r4[6], r4[7]);
        if (t < 18) {                         // halo jj in [0,8] u [521,529]
            int jj = (t < 9) ? t : (512 + t);
            float s0 = 0.f, s4 = 0.f;
#pragma unroll
            for (int k = 0; k < 8; ++k) {
                int i = 2 * jj + 3 + k;
                float v = xs[4 * SW(i >> 2) + (i & 3)];
                s0 += v * lo[k]; s4 += v * hi[k];
            }
            int s = jj + 3;
            as0[4 * SW(s >> 2) + (s & 3)] = s0;
            as1[4 * SW(s >> 2) + (s & 3)] = s4;
        }
        size_t o = (size_t)bi * 65536 + (size_t)N1 + 8 * (size_t)t;
        *(float4*)(out + o)             = make_float4(r0[0], r0[1], r0[2], r0[3]);
        *(float4*)(out + o + 4)         = make_float4(r0[4], r0[5], r0[6], r0[7]);
        *(float4*)(out + o + 32768)     = make_float4(r4[0], r4[1], r4[2], r4[3]);
        *(float4*)(out + o + 32768 + 4) = make_float4(r4[4], r4[5], r4[6], r4[7]);
    }

    __syncthreads();

    // ---- level 2: b[m] = sum_k a_local[2m+k] * w ; main m = 4t+3..4t+6 ----
    {
        alignas(16) float av0[16], av1[16];   // av[i] = a_store[8t+8+i]
#pragma unroll
        for (int j = 0; j < 4; ++j) {
            *(float4*)(av0 + 4 * j) = *(const float4*)(as0 + 4 * SW(2 * t + 2 + j));
            *(float4*)(av1 + 4 * j) = *(const float4*)(as1 + 4 * SW(2 * t + 2 + j));
        }
        float v0[4], v2[4], v4[4], v6[4];
#pragma unroll
        for (int i = 0; i < 4; ++i) {
            float s0 = 0.f, s2 = 0.f, s4 = 0.f, s6 = 0.f;
#pragma unroll
            for (int k = 0; k < 8; ++k) {
                float a0 = av0[2 * i + 1 + k], a4 = av1[2 * i + 1 + k];
                s0 += a0 * lo[k]; s2 += a0 * hi[k];
                s4 += a4 * lo[k]; s6 += a4 * hi[k];
            }
            v0[i] = s0; v2[i] = s2; v4[i] = s4; v6[i] = s6;
        }
        // bs_store s = m+1 -> quad t+1
        *(float4*)(bs0 + 4 * SW(t + 1)) = make_float4(v0[0], v0[1], v0[2], v0[3]);
        *(float4*)(bs1 + 4 * SW(t + 1)) = make_float4(v2[0], v2[1], v2[2], v2[3]);
        *(float4*)(bs2 + 4 * SW(t + 1)) = make_float4(v4[0], v4[1], v4[2], v4[3]);
        *(float4*)(bs3 + 4 * SW(t + 1)) = make_float4(v6[0], v6[1], v6[2], v6[3]);
        if (t < 6) {                          // halo m in [0,2] u [259,261]
            int m = (t < 3) ? t : (256 + t);
            float s0 = 0.f, s2 = 0.f, s4 = 0.f, s6 = 0.f;
#pragma unroll
            for (int k = 0; k < 8; ++k) {
                int i = 2 * m + 3 + k;        // a_store index
                float a0 = as0[4 * SW(i >> 2) + (i & 3)];
                float a4 = as1[4 * SW(i >> 2) + (i & 3)];
                s0 += a0 * lo[k]; s2 += a0 * hi[k];
                s4 += a4 * lo[k]; s6 += a4 * hi[k];
            }
            int s = m + 1;
            bs0[4 * SW(s >> 2) + (s & 3)] = s0;
            bs1[4 * SW(s >> 2) + (s & 3)] = s2;
            bs2[4 * SW(s >> 2) + (s & 3)] = s4;
            bs3[4 * SW(s >> 2) + (s & 3)] = s6;
        }
        // order [b0, b2, b6, b4]
        size_t o = 8388608ull + (size_t)bi * 65536 + (size_t)N2 + 4 * (size_t)t;
        *(float4*)(out + o)             = make_float4(v0[0], v0[1], v0[2], v0[3]);
        *(float4*)(out + o + 16384)     = make_float4(v2[0], v2[1], v2[2], v2[3]);
        *(float4*)(out + o + 2 * 16384) = make_float4(v6[0], v6[1], v6[2], v6[3]);
        *(float4*)(out + o + 3 * 16384) = make_float4(v4[0], v4[1], v4[2], v4[3]);
    }

    __syncthreads();

    // ---- level 3: c[p] = sum_k b_local[2p+k] * w ; p = 2t + {0,1} ----
    {
        alignas(16) float bv0[12], bv1[12], bv2[12], bv3[12];  // bv[i]=bs_store[4t+i]
#pragma unroll
        for (int j = 0; j < 3; ++j) {
            *(float4*)(bv0 + 4 * j) = *(const float4*)(bs0 + 4 * SW(t + j));
            *(float4*)(bv1 + 4 * j) = *(const float4*)(bs1 + 4 * SW(t + j));
            *(float4*)(bv2 + 4 * j) = *(const float4*)(bs2 + 4 * SW(t + j));
            *(float4*)(bv3 + 4 * j) = *(const float4*)(bs3 + 4 * SW(t + j));
        }
        float c0[2], c1[2], c2[2], c3[2], c4[2], c5[2], c6[2], c7[2];
#pragma unroll
        for (int j = 0; j < 2; ++j) {
            float s0 = 0.f, s1 = 0.f, s2 = 0.f, s3 = 0.f;
            float s4 = 0.f, s5 = 0.f, s6 = 0.f, s7 = 0.f;
#pragma unroll
            for (int k = 0; k < 8; ++k) {
                float b0 = bv0[2 * j + 1 + k], b2 = bv1[2 * j + 1 + k];
                float b4 = bv2[2 * j + 1 + k], b6 = bv3[2 * j + 1 + k];
                s0 += b0 * lo[k]; s1 += b0 * hi[k];
                s2 += b2 * lo[k]; s3 += b2 * hi[k];
                s4 += b4 * lo[k]; s5 += b4 * hi[k];
                s6 += b6 * lo[k]; s7 += b6 * hi[k];
            }
            c0[j] = s0; c1[j] = s1; c2[j] = s2; c3[j] = s3;
            c4[j] = s4; c5[j] = s5; c6[j] = s6; c7[j] = s7;
        }
        // order [c0, c1, c3, c2, c6, c7, c5, c4]
        size_t o = 16777216ull + (size_t)bi * 65536 + (size_t)N3 + 2 * (size_t)t;
        *(float2*)(out + o)            = make_float2(c0[0], c0[1]);
        *(float2*)(out + o + 8192)     = make_float2(c1[0], c1[1]);
        *(float2*)(out + o + 2 * 8192) = make_float2(c3[0], c3[1]);
        *(float2*)(out + o + 3 * 8192) = make_float2(c2[0], c2[1]);
        *(float2*)(out + o + 4 * 8192) = make_float2(c6[0], c6[1]);
        *(float2*)(out + o + 5 * 8192) = make_float2(c7[0], c7[1]);
        *(float2*)(out + o + 6 * 8192) = make_float2(c5[0], c5[1]);
        *(float2*)(out + o + 7 * 8192) = make_float2(c4[0], c4[1]);
    }
}

extern "C" void kernel_launch(void* const* d_in, const int* in_sizes, int n_in,
                              void* d_out, int out_size, void* d_ws, size_t ws_size,
                              hipStream_t stream) {
    const float* x   = (const float*)d_in[0];
    const float* ker = (const float*)d_in[1];
    float* out = (float*)d_out;
    dim3 grid(64, 128), block(64);
    hipLaunchKernelGGL(mwpt_kernel, grid, block, 0, stream, x, ker, out);
}